// Round 1
// baseline (166.064 us; speedup 1.0000x reference)
//
#include <hip/hip_runtime.h>

#define NTOK 16384
#define DIM  512
#define NEXP 8
#define TOPK 2
#define NCAP NTOK            // per-expert segment capacity (max tokens/expert = N)
#define NITEMS (NTOK*TOPK)

#define BM 128
#define BN 128
#define BK 32
#define LDT 40               // padded LDS row stride in bf16 elems (32 + 8 -> 16B aligned, 2-way banks only)

typedef __bf16 bf16x8 __attribute__((ext_vector_type(8)));
typedef __bf16 bf16x4 __attribute__((ext_vector_type(4)));
typedef float  f32x4  __attribute__((ext_vector_type(4)));

// ---------------- K0: zero expert cursors ----------------
__global__ void k_init(int* __restrict__ cursor) {
    if (threadIdx.x < NEXP) cursor[threadIdx.x] = 0;
}

// ---------------- K1: W [E][k][o] fp32 -> Wt [E][o][k] bf16 (transpose+convert) ----------------
__global__ __launch_bounds__(256) void k_wt(const float* __restrict__ W,
                                            __bf16* __restrict__ Wt) {
    __shared__ __bf16 tile[32][34];   // pad to 34 to break bank conflicts
    int e = blockIdx.z;
    int o0 = blockIdx.x * 32;
    int k0 = blockIdx.y * 32;
    const float* Wsrc = W + ((size_t)e * DIM + k0) * DIM + o0;
    for (int idx = threadIdx.x; idx < 1024; idx += 256) {
        int kk = idx >> 5, oo = idx & 31;           // consecutive tid -> consecutive oo: coalesced
        tile[oo][kk] = (__bf16)Wsrc[(size_t)kk * DIM + oo];
    }
    __syncthreads();
    __bf16* Wdst = Wt + ((size_t)e * DIM + o0) * DIM + k0;
    for (int idx = threadIdx.x; idx < 1024; idx += 256) {
        int oo = idx >> 5, kk = idx & 31;           // consecutive tid -> consecutive kk: contiguous
        Wdst[(size_t)oo * DIM + kk] = tile[oo][kk];
    }
}

// ---------------- K2: routing scatter (counting sort into fixed segments) ----------------
__global__ __launch_bounds__(256) void k_route(const int* __restrict__ indices,
                                               const float* __restrict__ probs,
                                               int* __restrict__ cursor,
                                               int* __restrict__ slot_arr,
                                               float* __restrict__ wgt_arr) {
    __shared__ int lcnt[NEXP], lbase[NEXP];
    int tid = threadIdx.x;
    int t = blockIdx.x * 256 + tid;                 // item id = n*TOPK + k  (grid exactly covers NITEMS)
    if (tid < NEXP) lcnt[tid] = 0;
    __syncthreads();
    int   e = indices[t];
    float p = probs[t];
    int lr = atomicAdd(&lcnt[e], 1);                // local rank within block
    __syncthreads();
    if (tid < NEXP) lbase[tid] = atomicAdd(&cursor[tid], lcnt[tid]);  // 8 global atomics / block
    __syncthreads();
    int pos = e * NCAP + lbase[e] + lr;
    slot_arr[pos] = t;                              // token = t>>1, dest slot = t
    wgt_arr[pos]  = p;
}

// ---------------- K3: grouped GEMM  partial[slot] = p * (x[tok] @ W[e] + b[e]) ----------------
__global__ __launch_bounds__(256) void k_gemm(const float* __restrict__ x,
                                              const __bf16* __restrict__ Wt,
                                              const float* __restrict__ bias,
                                              const int* __restrict__ slot_arr,
                                              const float* __restrict__ wgt_arr,
                                              const int* __restrict__ cnt,
                                              float* __restrict__ partial) {
    int e = blockIdx.z;
    int count = cnt[e];
    int m0 = blockIdx.y * BM;
    if (m0 >= count) return;                        // inactive tile: early exit
    int n0 = blockIdx.x * BN;
    int tid = threadIdx.x;

    __shared__ __attribute__((aligned(16))) __bf16 sA[BM * LDT];
    __shared__ __attribute__((aligned(16))) __bf16 sB[BN * LDT];
    __shared__ int   sslot[BM];
    __shared__ float swgt[BM];

    if (tid < BM) {
        int g = m0 + tid;
        int s = 0; float w = 0.f;
        if (g < count) { s = slot_arr[e * NCAP + g]; w = wgt_arr[e * NCAP + g]; }
        sslot[tid] = s;                             // invalid rows alias token 0 (loads safe, store skipped)
        swgt[tid]  = w;
    }
    __syncthreads();

    int wid  = tid >> 6, lane = tid & 63;
    int quad = lane >> 4, rr  = lane & 15;
    int wm = (wid >> 1) * 64, wn = (wid & 1) * 64;  // 2x2 waves over 128x128

    const __bf16* wt_e = Wt + (size_t)e * DIM * DIM;

    f32x4 acc[4][4] = {};

    for (int kt = 0; kt < DIM / BK; ++kt) {
        int k0 = kt * BK;
        // stage A: 128 rows x 32 k, gathered fp32 -> bf16.  1024 float4-chunks / 256 thr = 4 iters
        #pragma unroll
        for (int it = 0; it < 4; ++it) {
            int c  = tid + it * 256;
            int r  = c >> 3;
            int kc = (c & 7) << 2;
            int tok = sslot[r] >> 1;
            const float4 v = *(const float4*)(x + (size_t)tok * DIM + k0 + kc);
            bf16x4 h; h[0] = (__bf16)v.x; h[1] = (__bf16)v.y; h[2] = (__bf16)v.z; h[3] = (__bf16)v.w;
            *(bf16x4*)&sA[r * LDT + kc] = h;
        }
        // stage B: 128 o-rows x 32 k bf16 (already transposed).  512 16B-chunks / 256 thr = 2 iters
        #pragma unroll
        for (int it = 0; it < 2; ++it) {
            int c  = tid + it * 256;
            int o  = c >> 2;
            int kc = (c & 3) << 3;
            bf16x8 v = *(const bf16x8*)(wt_e + (size_t)(n0 + o) * DIM + k0 + kc);
            *(bf16x8*)&sB[o * LDT + kc] = v;
        }
        __syncthreads();
        bf16x8 af[4], bfr[4];
        #pragma unroll
        for (int i = 0; i < 4; ++i)
            af[i] = *(bf16x8*)&sA[(wm + i * 16 + rr) * LDT + quad * 8];   // A[m=lane&15][k=quad*8+j]
        #pragma unroll
        for (int j = 0; j < 4; ++j)
            bfr[j] = *(bf16x8*)&sB[(wn + j * 16 + rr) * LDT + quad * 8];  // B[k=quad*8+j][n=lane&15]
        #pragma unroll
        for (int i = 0; i < 4; ++i)
            #pragma unroll
            for (int j = 0; j < 4; ++j)
                acc[i][j] = __builtin_amdgcn_mfma_f32_16x16x32_bf16(af[i], bfr[j], acc[i][j], 0, 0, 0);
        __syncthreads();
    }

    // epilogue: C/D layout col=lane&15, row=quad*4+reg.  partial[slot][col] = (acc + b)*p
    float bv[4];
    #pragma unroll
    for (int j = 0; j < 4; ++j) bv[j] = bias[e * DIM + n0 + wn + j * 16 + rr];
    #pragma unroll
    for (int i = 0; i < 4; ++i) {
        #pragma unroll
        for (int reg = 0; reg < 4; ++reg) {
            int row = wm + i * 16 + quad * 4 + reg;
            int g = m0 + row;
            if (g >= count) continue;
            int   s = sslot[row];
            float w = swgt[row];
            float* dst = partial + (size_t)s * DIM + n0 + wn + rr;
            #pragma unroll
            for (int j = 0; j < 4; ++j)
                dst[j * 16] = (acc[i][j][reg] + bv[j]) * w;
        }
    }
}

// ---------------- K4: combine the two slots per token + loss ----------------
__global__ __launch_bounds__(256) void k_combine(const float* __restrict__ partial,
                                                 float* __restrict__ out) {
    int t = blockIdx.x * blockDim.x + threadIdx.x;
    const float4* p4 = (const float4*)partial;
    float4* o4 = (float4*)out;
    const int total4 = NTOK * DIM / 4;              // 2,097,152
    for (int i = t; i < total4; i += gridDim.x * blockDim.x) {
        int n  = i >> 7;                            // 128 float4 per D-row
        int d4 = i & 127;
        float4 a = p4[((size_t)n << 8) + d4];
        float4 c = p4[((size_t)n << 8) + 128 + d4];
        float4 r; r.x = a.x + c.x; r.y = a.y + c.y; r.z = a.z + c.z; r.w = a.w + c.w;
        o4[i] = r;
    }
    if (t == 0) out[NTOK * DIM] = 0.0f;             // total_loss
}

extern "C" void kernel_launch(void* const* d_in, const int* in_sizes, int n_in,
                              void* d_out, int out_size, void* d_ws, size_t ws_size,
                              hipStream_t stream) {
    const float* x    = (const float*)d_in[0];   // [N, D]
    const float* prob = (const float*)d_in[1];   // [N, K]
    const int*   idx  = (const int*)d_in[2];     // [N, K]
    const float* W    = (const float*)d_in[3];   // [E, D, D]
    const float* b    = (const float*)d_in[4];   // [E, D]
    float* out = (float*)d_out;                  // [N*D + 1]

    // workspace layout (all 256B aligned):
    //   Wt      : E*D*D bf16      = 4,194,304 B
    //   cursor  : 8 int           (256 B reserved)
    //   slot_arr: E*NCAP int      =   524,288 B
    //   wgt_arr : E*NCAP float    =   524,288 B
    //   partial : N*K*D float     = 67,108,864 B        total ~72.4 MB
    char* ws = (char*)d_ws;
    __bf16* Wt       = (__bf16*)ws;
    int*    cursor   = (int*)   (ws + 4194304);
    int*    slot_arr = (int*)   (ws + 4194304 + 256);
    float*  wgt_arr  = (float*) (ws + 4194304 + 256 + 524288);
    float*  partial  = (float*) (ws + 4194304 + 256 + 2 * 524288);

    hipLaunchKernelGGL(k_init,    dim3(1),                          dim3(64),  0, stream, cursor);
    hipLaunchKernelGGL(k_wt,      dim3(16, 16, 8),                  dim3(256), 0, stream, W, Wt);
    hipLaunchKernelGGL(k_route,   dim3(NITEMS / 256),               dim3(256), 0, stream,
                       idx, prob, cursor, slot_arr, wgt_arr);
    hipLaunchKernelGGL(k_gemm,    dim3(DIM / BN, NTOK / BM, NEXP),  dim3(256), 0, stream,
                       x, Wt, b, slot_arr, wgt_arr, cursor, partial);
    hipLaunchKernelGGL(k_combine, dim3(2048),                       dim3(256), 0, stream, partial, out);
}

// Round 2
// 161.866 us; speedup vs baseline: 1.0259x; 1.0259x over previous
//
#include <hip/hip_runtime.h>

#define NTOK 16384
#define DIM  512
#define NEXP 8
#define TOPK 2
#define NCAP NTOK            // per-expert segment capacity (max tokens/expert = N)
#define NITEMS (NTOK*TOPK)

#define BM 128
#define BN 128
#define BK 32
#define LDT 40               // padded LDS row stride in bf16 elems (2-way bank alias only = free)

typedef __bf16 bf16x8 __attribute__((ext_vector_type(8)));
typedef __bf16 bf16x4 __attribute__((ext_vector_type(4)));
typedef float  f32x4  __attribute__((ext_vector_type(4)));

// ---------------- K1: prep — W [E][k][o] f32 -> Wt [E][o][k] bf16, and x f32 -> xb bf16 ----------------
__global__ __launch_bounds__(256) void k_prep(const float* __restrict__ W,
                                              __bf16* __restrict__ Wt,
                                              const float* __restrict__ x,
                                              __bf16* __restrict__ xb) {
    if (blockIdx.z == NEXP) {
        // x convert plane: 16x16 = 256 blocks x 256 threads; 2,097,152 float4 total -> 32/thread
        int base = (blockIdx.y * 16 + blockIdx.x) * 256 + threadIdx.x;
        const float4* src = (const float4*)x;
        #pragma unroll
        for (int it = 0; it < 32; ++it) {
            int i = base + it * 65536;
            float4 v = src[i];
            bf16x4 h; h[0] = (__bf16)v.x; h[1] = (__bf16)v.y; h[2] = (__bf16)v.z; h[3] = (__bf16)v.w;
            *(bf16x4*)&xb[(size_t)i * 4] = h;
        }
        return;
    }
    __shared__ __bf16 tile[32][34];   // pad to 34 to break transpose bank conflicts
    int e = blockIdx.z;
    int o0 = blockIdx.x * 32;
    int k0 = blockIdx.y * 32;
    const float* Wsrc = W + ((size_t)e * DIM + k0) * DIM + o0;
    for (int idx = threadIdx.x; idx < 1024; idx += 256) {
        int kk = idx >> 5, oo = idx & 31;           // consecutive tid -> consecutive oo: coalesced
        tile[oo][kk] = (__bf16)Wsrc[(size_t)kk * DIM + oo];
    }
    __syncthreads();
    __bf16* Wdst = Wt + ((size_t)e * DIM + o0) * DIM + k0;
    for (int idx = threadIdx.x; idx < 1024; idx += 256) {
        int oo = idx >> 5, kk = idx & 31;           // consecutive tid -> consecutive kk: contiguous
        Wdst[(size_t)oo * DIM + kk] = tile[oo][kk];
    }
}

// ---------------- K2: routing scatter (counting sort into fixed segments) ----------------
__global__ __launch_bounds__(256) void k_route(const int* __restrict__ indices,
                                               const float* __restrict__ probs,
                                               int* __restrict__ cursor,
                                               int* __restrict__ slot_arr,
                                               float* __restrict__ wgt_arr) {
    __shared__ int lcnt[NEXP], lbase[NEXP];
    int tid = threadIdx.x;
    int t = blockIdx.x * 256 + tid;                 // item id = n*TOPK + k  (grid exactly covers NITEMS)
    if (tid < NEXP) lcnt[tid] = 0;
    __syncthreads();
    int   e = indices[t];
    float p = probs[t];
    int lr = atomicAdd(&lcnt[e], 1);                // local rank within block
    __syncthreads();
    if (tid < NEXP) lbase[tid] = atomicAdd(&cursor[tid], lcnt[tid]);  // 8 global atomics / block
    __syncthreads();
    int pos = e * NCAP + lbase[e] + lr;
    slot_arr[pos] = t;                              // token = t>>1, dest slot = t
    wgt_arr[pos]  = p;
}

// ---------------- K3: grouped GEMM  partial[slot] = bf16( p * (x[tok] @ W[e] + b[e]) ) ----------------
// 1D grid, XCD-swizzled: the 4 n-tiles of one m-tile all map to blockIdx % 8 == const,
// so (with round-robin block->XCD placement) they share one XCD's L2 -> x fetched ~once.
__global__ __launch_bounds__(256) void k_gemm(const __bf16* __restrict__ xb,
                                              const __bf16* __restrict__ Wt,
                                              const float* __restrict__ bias,
                                              const int* __restrict__ slot_arr,
                                              const float* __restrict__ wgt_arr,
                                              const int* __restrict__ cnt,
                                              __bf16* __restrict__ partial) {
    int p  = blockIdx.x;
    int r  = p & 7;
    int t  = p >> 3;
    int nt = t & 3;
    int g  = t >> 2;
    int m_glob = g * 8 + r;                         // global m-tile id over all experts
    int e   = m_glob >> 7;                          // 128 m-tiles per expert
    int m_t = m_glob & 127;
    int count = cnt[e];
    int m0 = m_t * BM;
    if (m0 >= count) return;                        // inactive tile: early exit
    int n0 = nt * BN;
    int tid = threadIdx.x;

    __shared__ __attribute__((aligned(16))) __bf16 sA[BM * LDT];
    __shared__ __attribute__((aligned(16))) __bf16 sB[BN * LDT];
    __shared__ int   sslot[BM];
    __shared__ float swgt[BM];

    if (tid < BM) {
        int gidx = m0 + tid;
        int s = 0; float w = 0.f;
        if (gidx < count) { s = slot_arr[e * NCAP + gidx]; w = wgt_arr[e * NCAP + gidx]; }
        sslot[tid] = s;                             // invalid rows alias token 0 (loads safe, store skipped)
        swgt[tid]  = w;
    }
    __syncthreads();

    int wid  = tid >> 6, lane = tid & 63;
    int quad = lane >> 4, rr  = lane & 15;
    int wm = (wid >> 1) * 64, wn = (wid & 1) * 64;  // 2x2 waves over 128x128

    const __bf16* wt_e = Wt + (size_t)e * DIM * DIM;

    f32x4 acc[4][4] = {};

    for (int kt = 0; kt < DIM / BK; ++kt) {
        int k0 = kt * BK;
        // stage A: 128 rows x 32 k bf16, gathered 16B chunks. 512 chunks / 256 thr = 2 iters
        #pragma unroll
        for (int it = 0; it < 2; ++it) {
            int c  = tid + it * 256;
            int rI = c >> 2;
            int kc = (c & 3) << 3;
            int tok = sslot[rI] >> 1;
            bf16x8 v = *(const bf16x8*)(xb + (size_t)tok * DIM + k0 + kc);
            *(bf16x8*)&sA[rI * LDT + kc] = v;
        }
        // stage B: 128 o-rows x 32 k bf16 (pre-transposed). 512 chunks / 256 thr = 2 iters
        #pragma unroll
        for (int it = 0; it < 2; ++it) {
            int c  = tid + it * 256;
            int o  = c >> 2;
            int kc = (c & 3) << 3;
            bf16x8 v = *(const bf16x8*)(wt_e + (size_t)(n0 + o) * DIM + k0 + kc);
            *(bf16x8*)&sB[o * LDT + kc] = v;
        }
        __syncthreads();
        bf16x8 af[4], bfr[4];
        #pragma unroll
        for (int i = 0; i < 4; ++i)
            af[i] = *(bf16x8*)&sA[(wm + i * 16 + rr) * LDT + quad * 8];   // A[m=lane&15][k=quad*8+j]
        #pragma unroll
        for (int j = 0; j < 4; ++j)
            bfr[j] = *(bf16x8*)&sB[(wn + j * 16 + rr) * LDT + quad * 8];  // B[k=quad*8+j][n=lane&15]
        #pragma unroll
        for (int i = 0; i < 4; ++i)
            #pragma unroll
            for (int j = 0; j < 4; ++j)
                acc[i][j] = __builtin_amdgcn_mfma_f32_16x16x32_bf16(af[i], bfr[j], acc[i][j], 0, 0, 0);
        __syncthreads();
    }

    // epilogue: C/D layout col=lane&15, row=quad*4+reg.  partial[slot][col] = bf16((acc + b)*p)
    float bv[4];
    #pragma unroll
    for (int j = 0; j < 4; ++j) bv[j] = bias[e * DIM + n0 + wn + j * 16 + rr];
    #pragma unroll
    for (int i = 0; i < 4; ++i) {
        #pragma unroll
        for (int reg = 0; reg < 4; ++reg) {
            int row = wm + i * 16 + quad * 4 + reg;
            int gidx = m0 + row;
            if (gidx >= count) continue;
            int   s = sslot[row];
            float w = swgt[row];
            __bf16* dst = partial + (size_t)s * DIM + n0 + wn + rr;
            #pragma unroll
            for (int j = 0; j < 4; ++j)
                dst[j * 16] = (__bf16)((acc[i][j][reg] + bv[j]) * w);
        }
    }
}

// ---------------- K4: combine the two bf16 slots per token -> fp32 out + loss ----------------
__global__ __launch_bounds__(256) void k_combine(const __bf16* __restrict__ partial,
                                                 float* __restrict__ out) {
    int t = blockIdx.x * blockDim.x + threadIdx.x;
    const int total8 = NTOK * DIM / 8;              // 1,048,576 chunks of 8
    for (int i = t; i < total8; i += gridDim.x * blockDim.x) {
        int n  = i >> 6;                            // 64 bf16x8-chunks per D-row
        int d8 = (i & 63) << 3;
        bf16x8 a = *(const bf16x8*)(partial + ((size_t)(2 * n)     * DIM) + d8);
        bf16x8 c = *(const bf16x8*)(partial + ((size_t)(2 * n + 1) * DIM) + d8);
        float4 lo, hi;
        lo.x = (float)a[0] + (float)c[0]; lo.y = (float)a[1] + (float)c[1];
        lo.z = (float)a[2] + (float)c[2]; lo.w = (float)a[3] + (float)c[3];
        hi.x = (float)a[4] + (float)c[4]; hi.y = (float)a[5] + (float)c[5];
        hi.z = (float)a[6] + (float)c[6]; hi.w = (float)a[7] + (float)c[7];
        float* o = out + (size_t)n * DIM + d8;
        *(float4*)o       = lo;
        *(float4*)(o + 4) = hi;
    }
    if (t == 0) out[NTOK * DIM] = 0.0f;             // total_loss
}

extern "C" void kernel_launch(void* const* d_in, const int* in_sizes, int n_in,
                              void* d_out, int out_size, void* d_ws, size_t ws_size,
                              hipStream_t stream) {
    const float* x    = (const float*)d_in[0];   // [N, D]
    const float* prob = (const float*)d_in[1];   // [N, K]
    const int*   idx  = (const int*)d_in[2];     // [N, K]
    const float* W    = (const float*)d_in[3];   // [E, D, D]
    const float* b    = (const float*)d_in[4];   // [E, D]
    float* out = (float*)d_out;                  // [N*D + 1]

    // workspace layout:
    //   Wt      : E*D*D bf16   =  4,194,304 B
    //   xb      : N*D bf16     = 16,777,216 B
    //   cursor  : 8 int        (256 B reserved)
    //   slot_arr: E*NCAP int   =    524,288 B
    //   wgt_arr : E*NCAP float =    524,288 B
    //   partial : N*K*D bf16   = 33,554,432 B     total ~55.6 MB
    char* ws = (char*)d_ws;
    __bf16* Wt       = (__bf16*)ws;
    __bf16* xb       = (__bf16*)(ws + 4194304);
    int*    cursor   = (int*)   (ws + 4194304 + 16777216);
    int*    slot_arr = (int*)   (ws + 4194304 + 16777216 + 256);
    float*  wgt_arr  = (float*) (ws + 4194304 + 16777216 + 256 + 524288);
    __bf16* partial  = (__bf16*)(ws + 4194304 + 16777216 + 256 + 2 * 524288);

    hipMemsetAsync(cursor, 0, NEXP * sizeof(int), stream);
    hipLaunchKernelGGL(k_prep,    dim3(16, 16, NEXP + 1), dim3(256), 0, stream, W, Wt, x, xb);
    hipLaunchKernelGGL(k_route,   dim3(NITEMS / 256),     dim3(256), 0, stream,
                       idx, prob, cursor, slot_arr, wgt_arr);
    hipLaunchKernelGGL(k_gemm,    dim3(4096),             dim3(256), 0, stream,
                       xb, Wt, b, slot_arr, wgt_arr, cursor, partial);
    hipLaunchKernelGGL(k_combine, dim3(2048),             dim3(256), 0, stream, partial, out);
}